// Round 1
// baseline (650.852 us; speedup 1.0000x reference)
//
#include <hip/hip_runtime.h>

#define FN 128
#define FE 64
#define KN 32

// K1: Bcat[g][c] (128 x 192): cols 0..63 = M[g,e] = sum_f wq[g,f]*wk[e,f]; cols 64..191 = wv[g,:]
__global__ __launch_bounds__(256) void build_bcat_kernel(
    const float* __restrict__ wq, const float* __restrict__ wk,
    const float* __restrict__ wv, float* __restrict__ bcat) {
  int idx = blockIdx.x * 256 + threadIdx.x;
  if (idx >= FN * 192) return;
  int g = idx / 192, c = idx % 192;
  float val;
  if (c < FE) {
    float s = 0.f;
#pragma unroll
    for (int f = 0; f < FE; ++f) s = fmaf(wq[g * FE + f], wk[c * FE + f], s);
    val = s;
  } else {
    val = wv[g * FN + (c - FE)];
  }
  bcat[idx] = val;
}

// K2: [t | vnodes] = nodes @ Bcat.  64-node tile in LDS, 8x6 register blocking.
__global__ __launch_bounds__(256) void tv_gemm_kernel(
    const float* __restrict__ nodes, const float* __restrict__ bcat,
    float* __restrict__ t_out, float* __restrict__ v_out, int N) {
  __shared__ float Asm[64][132];  // +4 pad: node-stride 132 -> 2-way max bank alias (free)
  const int tid = threadIdx.x;
  const int nbase = blockIdx.x * 64;
#pragma unroll
  for (int it = 0; it < 8; ++it) {
    int slot = it * 256 + tid;      // 2048 float4 slots
    int row = slot >> 5;            // 32 float4 per row
    int c4 = slot & 31;
    int gr = nbase + row;
    float4 v = make_float4(0.f, 0.f, 0.f, 0.f);
    if (gr < N) v = *reinterpret_cast<const float4*>(nodes + (size_t)gr * FN + c4 * 4);
    *reinterpret_cast<float4*>(&Asm[row][c4 * 4]) = v;
  }
  __syncthreads();
  const int tc = tid & 31;  // col group: cols tc*6 .. tc*6+5
  const int tr = tid >> 5;  // node group: nodes tr*8 .. tr*8+7
  float acc[8][6];
#pragma unroll
  for (int j = 0; j < 8; ++j)
#pragma unroll
    for (int i = 0; i < 6; ++i) acc[j][i] = 0.f;
  for (int g4 = 0; g4 < 32; ++g4) {
    float4 a4[8];
#pragma unroll
    for (int j = 0; j < 8; ++j)
      a4[j] = *reinterpret_cast<const float4*>(&Asm[tr * 8 + j][g4 * 4]);
#pragma unroll
    for (int gg = 0; gg < 4; ++gg) {
      const int g = g4 * 4 + gg;
      float b[6];
#pragma unroll
      for (int i = 0; i < 6; ++i) b[i] = bcat[g * 192 + tc * 6 + i];
#pragma unroll
      for (int j = 0; j < 8; ++j) {
        float a = (gg == 0) ? a4[j].x : (gg == 1) ? a4[j].y : (gg == 2) ? a4[j].z : a4[j].w;
#pragma unroll
        for (int i = 0; i < 6; ++i) acc[j][i] = fmaf(a, b[i], acc[j][i]);
      }
    }
  }
#pragma unroll
  for (int j = 0; j < 8; ++j) {
    int n = nbase + tr * 8 + j;
    if (n >= N) continue;
#pragma unroll
    for (int i = 0; i < 6; ++i) {
      int c = tc * 6 + i;
      if (c < FE) t_out[(size_t)n * FE + c] = acc[j][i];
      else        v_out[(size_t)n * FN + (c - FE)] = acc[j][i];
    }
  }
}

// K3: one wave per node: qdot -> softmax -> weighted gather of vnodes.
__global__ __launch_bounds__(256) void attn_gather_kernel(
    const float* __restrict__ edges, const int* __restrict__ nlist,
    const float* __restrict__ inv_degree, const float* __restrict__ t_in,
    const float* __restrict__ vnodes, float* __restrict__ out, int N) {
  __shared__ float smt[4][64];
  const int wave = threadIdx.x >> 6;
  const int lane = threadIdx.x & 63;
  int n = blockIdx.x * 4 + wave;
  if (n >= N) n = N - 1;  // duplicate work on valid row; stores same value (benign)

  float tl = t_in[(size_t)n * FE + lane];
  smt[wave][lane] = tl;
  __syncthreads();

  const float invd = inv_degree[n];
  int idxreg = 0;
  if (lane < KN) idxreg = nlist[(size_t)n * KN + lane];

  // lane = 2k+h: lane covers half-row h of edge row k  (all 64 lanes active)
  const int k = lane >> 1, h = lane & 1;
  const float* ep = edges + ((size_t)n * KN + k) * FE + h * 32;
  float partial = 0.f;
#pragma unroll
  for (int j = 0; j < 8; ++j) {
    float4 e4 = *reinterpret_cast<const float4*>(ep + j * 4);
    partial = fmaf(e4.x, smt[wave][h * 32 + j * 4 + 0], partial);
    partial = fmaf(e4.y, smt[wave][h * 32 + j * 4 + 1], partial);
    partial = fmaf(e4.z, smt[wave][h * 32 + j * 4 + 2], partial);
    partial = fmaf(e4.w, smt[wave][h * 32 + j * 4 + 3], partial);
  }
  float qd = (partial + __shfl_xor(partial, 1)) * invd;

  // butterfly over offsets 2..32: each parity class = each k exactly once
  float m = qd;
#pragma unroll
  for (int o = 2; o <= 32; o <<= 1) m = fmaxf(m, __shfl_xor(m, o));
  float p = __expf(qd - m);
  float s = p;
#pragma unroll
  for (int o = 2; o <= 32; o <<= 1) s += __shfl_xor(s, o);
  const float b = p / s;  // lane 2k+h holds b[k]

  float accx = 0.f, accy = 0.f;
#pragma unroll
  for (int kk = 0; kk < KN; ++kk) {
    float bk = __shfl(b, kk * 2);
    int ik = __shfl(idxreg, kk);
    const float2 v = *reinterpret_cast<const float2*>(vnodes + (size_t)ik * FN + lane * 2);
    accx = fmaf(bk, v.x, accx);
    accy = fmaf(bk, v.y, accy);
  }
  float2 res;
  res.x = accx;
  res.y = accy;
  *reinterpret_cast<float2*>(out + (size_t)n * FN + lane * 2) = res;
}

extern "C" void kernel_launch(void* const* d_in, const int* in_sizes, int n_in,
                              void* d_out, int out_size, void* d_ws, size_t ws_size,
                              hipStream_t stream) {
  const float* nodes      = (const float*)d_in[0];
  const int*   nlist      = (const int*)d_in[1];
  const float* edges      = (const float*)d_in[2];
  const float* inv_degree = (const float*)d_in[3];
  const float* wq         = (const float*)d_in[4];
  const float* wk         = (const float*)d_in[5];
  const float* wv         = (const float*)d_in[6];
  float* out = (float*)d_out;
  const int N = in_sizes[0] / FN;

  // ws layout (floats): Bcat[128*192] | t[N*64] | vnodes[N*128]  (~38.5 MB)
  float* ws    = (float*)d_ws;
  float* bcat  = ws;
  float* t_buf = ws + 128 * 192;
  float* v_buf = t_buf + (size_t)N * FE;

  build_bcat_kernel<<<(FN * 192 + 255) / 256, 256, 0, stream>>>(wq, wk, wv, bcat);
  tv_gemm_kernel<<<(N + 63) / 64, 256, 0, stream>>>(nodes, bcat, t_buf, v_buf, N);
  attn_gather_kernel<<<(N + 3) / 4, 256, 0, stream>>>(edges, nlist, inv_degree,
                                                      t_buf, v_buf, out, N);
}